// Round 21
// baseline (153.495 us; speedup 1.0000x reference)
//
#include <hip/hip_runtime.h>
#include <math.h>

// ---------------------------------------------------------------------------
// CSPN_Propagate — MI355X. Round 21:
//  * r19 config (149.7 us best: heavy-first conv, 16x16 cspn tiles, guarded
//    gather — r20's check-free path was noise-neutral, reverted).
//  * ONE change: prep dispatch deleted. RAW0's gt/blur/rgb fusion is folded
//    inline into cspn stage-0's staging loop (3 cached loads vs 1, stage 0 is
//    smallest); prep shrinks to a single-block weight-fragment kernel.
//    Removes one 1152-block dispatch + gap + RAW0 round-trip.
// ---------------------------------------------------------------------------

#define B 16
#define FH 256
#define FW 512
#define TH 16
#define TW 16
#define HALO 3
#define LD 22
#define GD 20
#define MAXC 2

typedef __attribute__((ext_vector_type(8))) short short8;
typedef __attribute__((ext_vector_type(4))) float f32x4;

// slot swizzle: 16B slot L = 2*cc + h  ->  L ^ (cc&1) ^ ((cc>>1)&2)
__device__ __forceinline__ int swzslot(int cc, int h) {
  return (((cc << 1) | h) ^ (cc & 1) ^ ((cc >> 1) & 2));
}

// ------------- tiny prep: split-bf16 weight fragments only ------------------
__global__ __launch_bounds__(64) void wf_kernel(
    const float* __restrict__ w0c, const float* __restrict__ w1c,
    const float* __restrict__ w2c, const float* __restrict__ w3c,
    short8* __restrict__ wf) {
  int lane = threadIdx.x;
  int px = lane & 15, g = lane >> 4;
  const float* Ws[4] = {w0c, w1c, w2c, w3c};
  for (int st = 0; st < 4; ++st) {
    const float* wgt = Ws[st];
    for (int t = 0; t < 5; ++t) {
      short8 wh, wl;
      for (int j = 0; j < 8; ++j) {
        int k = 32 * t + 8 * g + j;
        int s = k >> 4, ci = k & 15;
        float wv = 0.0f;
        if (px < 8 && s < 9) wv = wgt[(px * 16 + ci) * 9 + s];
        uint uw = __float_as_uint(wv);
        uint hw_ = (uw + 0x8000u) & 0xFFFF0000u;
        float wlo = wv - __uint_as_float(hw_);
        wh[j] = (short)(hw_ >> 16);
        wl[j] = (short)((__float_as_uint(wlo) + 0x8000u) >> 16);
      }
      wf[((st * 5 + t) * 2 + 0) * 64 + lane] = wh;
      wf[((st * 5 + t) * 2 + 1) * 64 + lane] = wl;
    }
  }
}

// -------- conv via MFMA: 32x16 tiles, heavy-first order, all stages ---------
// (r19 verbatim: verified 80 us, absmax 0.0039)
__global__ __launch_bounds__(256) void conv_mfma_kernel(
    const float* __restrict__ feat, const short8* __restrict__ wf,
    const float* __restrict__ b0c, float* __restrict__ g0,
    const float* __restrict__ b1c, float* __restrict__ g1,
    const float* __restrict__ b2c, float* __restrict__ g2,
    const float* __restrict__ b3c, float* __restrict__ g3) {
  __shared__ uint4 sH[18 * 72];
  __shared__ uint4 sL[18 * 72];

  // heavy-first tile order: s = sorted tile index (coverage 4,3,2,1),
  // batch-fastest so all batches' heavy tiles launch first.
  int bid = blockIdx.x;
  int s_ = bid >> 4, b = bid & 15;
  int by, bx;
  if (s_ < 36) {               // solid 6x6 center (coverage 4)
    by = 3 + s_ / 6; bx = 3 + s_ % 6;
  } else if (s_ < 64) {        // ring of 8x8 box [2..9] (coverage 3)
    int e = s_ - 36;
    if (e < 8)       { by = 2; bx = 2 + e; }
    else if (e < 16) { by = 9; bx = 2 + (e - 8); }
    else if (e < 22) { by = 3 + (e - 16); bx = 2; }
    else             { by = 3 + (e - 22); bx = 9; }
  } else if (s_ < 100) {       // ring of 10x10 box [1..10] (coverage 2)
    int e = s_ - 64;
    if (e < 10)      { by = 1; bx = 1 + e; }
    else if (e < 20) { by = 10; bx = 1 + (e - 10); }
    else if (e < 28) { by = 2 + (e - 20); bx = 1; }
    else             { by = 2 + (e - 28); bx = 10; }
  } else {                     // ring of 12x12 box [0..11] (coverage 1)
    int e = s_ - 100;
    if (e < 12)      { by = 0; bx = e; }
    else if (e < 24) { by = 11; bx = e - 12; }
    else if (e < 34) { by = 1 + (e - 24); bx = 0; }
    else             { by = 1 + (e - 34); bx = 11; }
  }
  int ty0 = by << 4, tx0 = bx << 5;

  int tid = threadIdx.x;
  int lane = tid & 63, wv = tid >> 6;
  int px = lane & 15, g = lane >> 4;
  int h_ = g & 1, gb = g >> 1;

  // ---- stage feature halo tile (34 x 18 x 16ci), truncation split ----
  const size_t FHW = (size_t)FH * FW;
  const float* fb = feat + (size_t)b * 16 * FHW;
  for (int u = tid; u < 612; u += 256) {
    int rr = u / 34, cc = u % 34;
    int yy = ty0 + rr - 1;
    yy = (yy < 0) ? 0 : ((yy > 191) ? 191 : yy);
    int xx = tx0 + cc - 1;
    xx = (xx < 0) ? 0 : ((xx > 383) ? 383 : xx);
    const float* fp = fb + (size_t)(32 + yy) * FW + (64 + xx);
    uint hiD[8], loD[8];
#pragma unroll
    for (int i = 0; i < 8; ++i) {
      float a0 = fp[(size_t)(2 * i) * FHW];
      float a1 = fp[(size_t)(2 * i + 1) * FHW];
      uint u0 = __float_as_uint(a0), u1 = __float_as_uint(a1);
      uint h0 = u0 & 0xFFFF0000u;
      uint h1 = u1 & 0xFFFF0000u;
      float l0 = a0 - __uint_as_float(h0);
      float l1 = a1 - __uint_as_float(h1);
      hiD[i] = (h0 >> 16) | h1;
      loD[i] = (__float_as_uint(l0) >> 16) | (__float_as_uint(l1) & 0xFFFF0000u);
    }
    int r72 = rr * 72;
    sH[r72 + swzslot(cc, 0)] = make_uint4(hiD[0], hiD[1], hiD[2], hiD[3]);
    sH[r72 + swzslot(cc, 1)] = make_uint4(hiD[4], hiD[5], hiD[6], hiD[7]);
    sL[r72 + swzslot(cc, 0)] = make_uint4(loD[0], loD[1], loD[2], loD[3]);
    sL[r72 + swzslot(cc, 1)] = make_uint4(loD[4], loD[5], loD[6], loD[7]);
  }
  __syncthreads();

  const short8* pH = (const short8*)sH;
  const short8* pL = (const short8*)sL;

  const int SH_[4] = {96, 128, 160, 192};
  const int SW_[4] = {192, 256, 320, 384};
  const int OY[4] = {48, 32, 16, 0};
  const int OX[4] = {96, 64, 32, 0};
  const float* BIAS[4] = {b0c, b1c, b2c, b3c};
  float* GD_[4] = {g0, g1, g2, g3};

#pragma unroll
  for (int st = 0; st < 4; ++st) {
    int sh = SH_[st], sw = SW_[st], oy = OY[st], ox = OX[st];
    bool inR = (ty0 >= oy) && (ty0 + 16 <= oy + sh) && (tx0 >= ox) &&
               (tx0 + 32 <= ox + sw);
    if (!inR) continue;  // block-uniform
    bool topE = (ty0 == oy), botE = (ty0 + 16 == oy + sh);
    bool leftE = (tx0 == ox), rightE = (tx0 + 32 == ox + sw);

    const short8* wfs = wf + st * 640;
    short8 WH[5], WL[5];
#pragma unroll
    for (int t = 0; t < 5; ++t) {
      WH[t] = wfs[(t * 2 + 0) * 64 + lane];
      WL[t] = wfs[(t * 2 + 1) * 64 + lane];
    }
    float bias4[4];
    {
      const float* bp = BIAS[st] + ((g & 1) << 2);
#pragma unroll
      for (int r = 0; r < 4; ++r) bias4[r] = bp[r];
    }
    size_t hw = (size_t)sh * sw;
    float* guid = GD_[st];

    // col-slot precompute (once per stage): xt in {0,1}, dx in {-1,0,+1}
    int csl[2][3];
#pragma unroll
    for (int xt = 0; xt < 2; ++xt) {
      int cc0 = (xt << 4) + px + 1;
      int ccm = (leftE && cc0 == 1) ? cc0 + 1 : cc0 - 1;
      int ccp = (rightE && cc0 == 32) ? cc0 - 1 : cc0 + 1;
      csl[xt][0] = swzslot(ccm, h_);
      csl[xt][1] = swzslot(cc0, h_);
      csl[xt][2] = swzslot(ccp, h_);
    }

#pragma unroll
    for (int i = 0; i < 8; ++i) {
      int tau = wv * 8 + i;
      int row = tau >> 1;
      const int xt = i & 1;  // wv*8 even -> compile-time per i
      int rr0 = row + 1;
      int rm = (topE && row == 0) ? rr0 + 1 : rr0 - 1;
      int rp = (botE && row == 15) ? rr0 - 1 : rr0 + 1;
      int rbm = rm * 72, rb_ = rr0 * 72, rbp = rp * 72;
      const int c0 = csl[xt][0], c1 = csl[xt][1], c2 = csl[xt][2];
      // E taps: (-1,-1)(-1,+1)(0,0)(+1,-1)(+1,+1); O: (-1,0)(0,-1)(0,+1)(+1,0)(dummy)
      int iE[5] = {rbm + c0, rbm + c2, rb_ + c1, rbp + c0, rbp + c2};
      int iO[5] = {rbm + c1, rb_ + c0, rb_ + c2, rbp + c1, rb_ + c1};

      f32x4 acc = {bias4[0], bias4[1], bias4[2], bias4[3]};
#pragma unroll
      for (int t = 0; t < 5; ++t) {
        int idx = gb ? iO[t] : iE[t];
        short8 fh = pH[idx];
        short8 fl = pL[idx];
        acc = __builtin_amdgcn_mfma_f32_16x16x32_bf16(WH[t], fh, acc, 0, 0, 0);
        acc = __builtin_amdgcn_mfma_f32_16x16x32_bf16(WH[t], fl, acc, 0, 0, 0);
        acc = __builtin_amdgcn_mfma_f32_16x16x32_bf16(WL[t], fh, acc, 0, 0, 0);
      }
      if (g < 2) {
        int ly = ty0 + row - oy, lx = tx0 + (xt << 4) + px - ox;
        float* gp = guid + (size_t)b * 8 * hw + (size_t)ly * sw + lx;
#pragma unroll
        for (int r = 0; r < 4; ++r) {
          int oo = g * 4 + r;
          float v = acc[r];
          v = (v > 0.0f) ? v : (__expf(v) - 1.0f);
          gp[(size_t)oo * hw] = v;
        }
      }
    }
  }
}

// ---------------- fused CSPN x3 with register gates: 16x16 tiles ------------
// stage0 != 0: staging computes the gt/blur/rgb fusion inline (RAW0 deleted).
__global__ __launch_bounds__(256) void cspn3_kernel(
    const float* __restrict__ guid, const float* __restrict__ raw,
    const float* __restrict__ rgb, const float* __restrict__ gt,
    const float* __restrict__ blur, float* __restrict__ dst, int h, int w,
    int hs, int wss, int h2, int w2, int ph, int pw, int last, int stage0,
    int py0, int py1, int px0, int px1) {
  __shared__ float sraw[LD * LD];
  __shared__ float s0[LD * LD];
  __shared__ float s1[LD * LD];

  int tpw = w / TW, tph = h / TH;
  int tile = blockIdx.x;
  int tx = tile % tpw;
  int t2 = tile / tpw;
  int ty = t2 % tph;
  int b = t2 / tph;
  int oy = ty * TH - HALO, ox = tx * TW - HALO;
  int tid = threadIdx.x;

  const float* rb = raw + (size_t)b * h * w;
  const float* rgb0 = rgb + ((size_t)b * 3) * FH * FW;

  for (int e = tid; e < LD * LD; e += 256) {
    int r = e / LD, c = e % LD;
    int gy = oy + r, gx = ox + c;
    bool in = (gy >= 0 && gy < h && gx >= 0 && gx < w);
    float v = 0.0f;
    if (in) {
      size_t cidx = (size_t)(hs + gy) * FW + (wss + gx);
      float dep = rgb0[cidx];
      if (stage0) {
        size_t gg = (size_t)b * FH * FW + cidx;
        float gv = gt[gg];
        float s = gv / blur[gg];
        float dl = (s > 1.2f || s < 0.8f) ? 0.0f : gv;
        v = (dl > 0.0f) ? dl : dep;
      } else {
        bool prev = (gy >= py0 && gy < py1 && gx >= px0 && gx < px1);
        v = prev ? rb[(size_t)gy * w + gx] : dep;
      }
    }
    sraw[e] = v;
  }
  __syncthreads();

  const int dy8[8] = {1, 1, 1, 0, 0, -1, -1, -1};
  const int dx8[8] = {1, 0, -1, 1, -1, 1, 0, -1};
  const int off8[8] = {LD + 1, LD, LD - 1, 1, -1, -LD + 1, -LD, -LD - 1};

  const float* gb = guid + (size_t)b * 8 * h * w;
  float cg[MAXC][8];
  float r0[MAXC];
  int adr[MAXC];
#pragma unroll
  for (int ch = 0; ch < MAXC; ++ch) {
    int p = tid + ch * 256;
    bool ok = p < GD * GD;
    int pp = ok ? p : 0;
    int py = pp / GD + 1, px = pp % GD + 1;
    adr[ch] = py * LD + px;
    int gy = oy + py, gx = ox + px;
    bool in = ok && gy >= 0 && gy < h && gx >= 0 && gx < w;
    float wsum = 0.0f, asum = 0.0f;
    float g[8];
#pragma unroll
    for (int k = 0; k < 8; ++k) {
      int ny = gy + dy8[k], nx = gx + dx8[k];
      bool nin = ok && ny >= 0 && ny < h && nx >= 0 && nx < w;
      float gk = nin ? gb[(size_t)k * h * w + (size_t)ny * w + nx] : 0.0f;
      g[k] = gk;
      wsum += gk;
      asum += fabsf(gk);
    }
    float inv = in ? (1.0f / asum) : 0.0f;
#pragma unroll
    for (int k = 0; k < 8; ++k) cg[ch][k] = g[k] * inv;
    r0[ch] = in ? (1.0f - wsum * inv) * sraw[adr[ch]] : 0.0f;
  }

  // ---- iter 1: sraw -> s0 over 20x20 ----
#pragma unroll
  for (int ch = 0; ch < MAXC; ++ch) {
    int p = tid + ch * 256;
    if (p < GD * GD) {
      float v = r0[ch];
#pragma unroll
      for (int k = 0; k < 8; ++k) v += cg[ch][k] * sraw[adr[ch] + off8[k]];
      s0[adr[ch]] = v;
    }
  }
  __syncthreads();

  // ---- iter 2: s0 -> s1 over [2,19]^2 ----
#pragma unroll
  for (int ch = 0; ch < MAXC; ++ch) {
    int p = tid + ch * 256;
    if (p < GD * GD) {
      int py = p / GD + 1, px = p % GD + 1;
      if (py >= 2 && py <= LD - 3 && px >= 2 && px <= LD - 3) {
        float v = r0[ch];
#pragma unroll
        for (int k = 0; k < 8; ++k) v += cg[ch][k] * s0[adr[ch] + off8[k]];
        s1[adr[ch]] = v;
      }
    }
  }
  __syncthreads();

  // ---- iter 3 + epilogue over the 16x16 core ----
#pragma unroll
  for (int ch = 0; ch < MAXC; ++ch) {
    int p = tid + ch * 256;
    if (p < GD * GD) {
      int py = p / GD + 1, px = p % GD + 1;
      if (py >= 3 && py <= LD - 4 && px >= 3 && px <= LD - 4) {
        float v = r0[ch];
#pragma unroll
        for (int k = 0; k < 8; ++k) v += cg[ch][k] * s1[adr[ch] + off8[k]];
        float dl = fminf(fmaxf(v, 0.0f), 1.0f);
        int gy = oy + py, gx = ox + px;
        if (last) {
          dst[((size_t)b * h + gy) * w + gx] = dl;
        } else {
          float dep = rgb0[(size_t)(hs + gy) * FW + (wss + gx)];
          dst[((size_t)b * h2 + (gy + ph)) * w2 + (gx + pw)] =
              (dl > 0.0f) ? dl : dep;
        }
      }
    }
  }
}

// ---------------------------------------------------------------------------
extern "C" void kernel_launch(void* const* d_in, const int* in_sizes, int n_in,
                              void* d_out, int out_size, void* d_ws,
                              size_t ws_size, hipStream_t stream) {
  (void)in_sizes; (void)n_in; (void)out_size; (void)ws_size;
  const float* feat = (const float*)d_in[0];
  const float* blur = (const float*)d_in[1];
  const float* gt = (const float*)d_in[2];
  const float* rgb = (const float*)d_in[3];
  const float* W[4] = {(const float*)d_in[5], (const float*)d_in[7],
                       (const float*)d_in[9], (const float*)d_in[11]};
  const float* Bs[4] = {(const float*)d_in[6], (const float*)d_in[8],
                        (const float*)d_in[10], (const float*)d_in[12]};
  float* out = (float*)d_out;

  float* G0 = (float*)d_ws;
  float* G1 = G0 + (size_t)B * 8 * 96 * 192;
  float* G2 = G1 + (size_t)B * 8 * 128 * 256;
  float* G3 = G2 + (size_t)B * 8 * 160 * 320;
  float* RAW[4];
  RAW[0] = G3 + (size_t)B * 8 * 192 * 384;  // RAW[0] slot unused (kept layout)
  RAW[1] = RAW[0] + (size_t)B * 96 * 192;
  RAW[2] = RAW[1] + (size_t)B * 128 * 256;
  RAW[3] = RAW[2] + (size_t)B * 160 * 320;
  short8* WF = (short8*)(RAW[3] + (size_t)B * 192 * 384);
  float* G[4] = {G0, G1, G2, G3};

  const int CH[4] = {96, 128, 160, 192};
  const int CW[4] = {192, 256, 320, 384};

  wf_kernel<<<1, 64, 0, stream>>>(W[0], W[1], W[2], W[3], WF);

  conv_mfma_kernel<<<2304, 256, 0, stream>>>(feat, WF, Bs[0], G0, Bs[1], G1,
                                             Bs[2], G2, Bs[3], G3);

  for (int i = 0; i < 4; ++i) {
    int h = CH[i], w = CW[i];
    int hs = (FH - h) / 2, wss = (FW - w) / 2;
    int ntiles = B * (h / TH) * (w / TW);
    int py0 = 0, py1 = h, px0 = 0, px1 = w;
    if (i > 0) { py0 = 16; py1 = h - 16; px0 = 32; px1 = w - 32; }
    int st0 = (i == 0) ? 1 : 0;
    if (i < 3) {
      int h2 = CH[i + 1], w2 = CW[i + 1];
      int ph = (h2 - h) / 2, pw = (w2 - w) / 2;
      cspn3_kernel<<<ntiles, 256, 0, stream>>>(
          G[i], RAW[i], rgb, gt, blur, RAW[i + 1], h, w, hs, wss, h2, w2, ph,
          pw, 0, st0, py0, py1, px0, px1);
    } else {
      cspn3_kernel<<<ntiles, 256, 0, stream>>>(
          G[i], RAW[i], rgb, gt, blur, out, h, w, hs, wss, h, w, 0, 0, 1, st0,
          py0, py1, px0, px1);
    }
  }
}

// Round 22
// 148.793 us; speedup vs baseline: 1.0316x; 1.0316x over previous
//
#include <hip/hip_runtime.h>
#include <math.h>

// ---------------------------------------------------------------------------
// CSPN_Propagate — MI355X. Round 22 = round 19 verbatim (best verified:
// 149.7 us, absmax 0.0039).
//  * conv: union one-pass MFMA (32x16 tiles), split-bf16 (hi/lo) operands,
//    3-MFMA/tap datapath, heavy-first block ordering (coverage 4/3/2/1) —
//    r19's ordering also cut conv FETCH 117->64 MB via L2 co-scheduling.
//  * cspn3: 16x16 tiles (machine-fill), register-hoisted normalized gates,
//    3 iterations in LDS ping-pong + fused next-raw epilogue.
//  * r20 (check-free gather) and r21 (prep fusion) were neutral/negative;
//    both reverted. Datapath plateaus: conv 80 us (Mfma 21/VALU 35/HBM 24%,
//    no pipe saturated, insensitive to all levers tried), cspn ~55 us
//    (serial RAW chain, L2-latency-bound, coop fusion rejected by capture).
// ---------------------------------------------------------------------------

#define B 16
#define FH 256
#define FW 512
#define TH 16
#define TW 16
#define HALO 3
#define LD 22
#define GD 20
#define MAXC 2

typedef __attribute__((ext_vector_type(8))) short short8;
typedef __attribute__((ext_vector_type(4))) float f32x4;

// slot swizzle: 16B slot L = 2*cc + h  ->  L ^ (cc&1) ^ ((cc>>1)&2)
__device__ __forceinline__ int swzslot(int cc, int h) {
  return (((cc << 1) | h) ^ (cc & 1) ^ ((cc >> 1) & 2));
}

// ------------- prep: RAW0 + split-bf16 weight fragments ---------------------
__global__ __launch_bounds__(256) void prep_all_kernel(
    const float* __restrict__ gt, const float* __restrict__ blur,
    const float* __restrict__ rgb, const float* __restrict__ w0c,
    const float* __restrict__ w1c, const float* __restrict__ w2c,
    const float* __restrict__ w3c, short8* __restrict__ wf,
    float* __restrict__ r0) {
  if (blockIdx.x == 0 && threadIdx.x < 64) {
    int lane = threadIdx.x;
    int px = lane & 15, g = lane >> 4;
    const float* Ws[4] = {w0c, w1c, w2c, w3c};
    for (int st = 0; st < 4; ++st) {
      const float* wgt = Ws[st];
      for (int t = 0; t < 5; ++t) {
        short8 wh, wl;
        for (int j = 0; j < 8; ++j) {
          int k = 32 * t + 8 * g + j;
          int s = k >> 4, ci = k & 15;
          float wv = 0.0f;
          if (px < 8 && s < 9) wv = wgt[(px * 16 + ci) * 9 + s];
          uint uw = __float_as_uint(wv);
          uint hw_ = (uw + 0x8000u) & 0xFFFF0000u;
          float wlo = wv - __uint_as_float(hw_);
          wh[j] = (short)(hw_ >> 16);
          wl[j] = (short)((__float_as_uint(wlo) + 0x8000u) >> 16);
        }
        wf[((st * 5 + t) * 2 + 0) * 64 + lane] = wh;
        wf[((st * 5 + t) * 2 + 1) * 64 + lane] = wl;
      }
    }
  }

  int idx = blockIdx.x * blockDim.x + threadIdx.x;
  const int n0 = B * 96 * 192;
  if (idx >= n0) return;
  const int h = 96, w = 192, hs = 80, ws = 160;
  int x = idx % w;
  int t = idx / w;
  int y = t % h;
  int b = t / h;
  size_t g = (size_t)b * FH * FW + (size_t)(hs + y) * FW + (ws + x);
  float dep = rgb[((size_t)b * 3) * FH * FW + (size_t)(hs + y) * FW + (ws + x)];
  float gv = gt[g];
  float s = gv / blur[g];
  float dl = (s > 1.2f || s < 0.8f) ? 0.0f : gv;
  r0[idx] = (dl > 0.0f) ? dl : dep;
}

// -------- conv via MFMA: 32x16 tiles, heavy-first order, all stages ---------
__global__ __launch_bounds__(256) void conv_mfma_kernel(
    const float* __restrict__ feat, const short8* __restrict__ wf,
    const float* __restrict__ b0c, float* __restrict__ g0,
    const float* __restrict__ b1c, float* __restrict__ g1,
    const float* __restrict__ b2c, float* __restrict__ g2,
    const float* __restrict__ b3c, float* __restrict__ g3) {
  __shared__ uint4 sH[18 * 72];
  __shared__ uint4 sL[18 * 72];

  // heavy-first tile order: s = sorted tile index (coverage 4,3,2,1),
  // batch-fastest so all batches' heavy tiles launch first.
  int bid = blockIdx.x;
  int s_ = bid >> 4, b = bid & 15;
  int by, bx;
  if (s_ < 36) {               // solid 6x6 center (coverage 4)
    by = 3 + s_ / 6; bx = 3 + s_ % 6;
  } else if (s_ < 64) {        // ring of 8x8 box [2..9] (coverage 3)
    int e = s_ - 36;
    if (e < 8)       { by = 2; bx = 2 + e; }
    else if (e < 16) { by = 9; bx = 2 + (e - 8); }
    else if (e < 22) { by = 3 + (e - 16); bx = 2; }
    else             { by = 3 + (e - 22); bx = 9; }
  } else if (s_ < 100) {       // ring of 10x10 box [1..10] (coverage 2)
    int e = s_ - 64;
    if (e < 10)      { by = 1; bx = 1 + e; }
    else if (e < 20) { by = 10; bx = 1 + (e - 10); }
    else if (e < 28) { by = 2 + (e - 20); bx = 1; }
    else             { by = 2 + (e - 28); bx = 10; }
  } else {                     // ring of 12x12 box [0..11] (coverage 1)
    int e = s_ - 100;
    if (e < 12)      { by = 0; bx = e; }
    else if (e < 24) { by = 11; bx = e - 12; }
    else if (e < 34) { by = 1 + (e - 24); bx = 0; }
    else             { by = 1 + (e - 34); bx = 11; }
  }
  int ty0 = by << 4, tx0 = bx << 5;

  int tid = threadIdx.x;
  int lane = tid & 63, wv = tid >> 6;
  int px = lane & 15, g = lane >> 4;
  int h_ = g & 1, gb = g >> 1;

  // ---- stage feature halo tile (34 x 18 x 16ci), truncation split ----
  const size_t FHW = (size_t)FH * FW;
  const float* fb = feat + (size_t)b * 16 * FHW;
  for (int u = tid; u < 612; u += 256) {
    int rr = u / 34, cc = u % 34;
    int yy = ty0 + rr - 1;
    yy = (yy < 0) ? 0 : ((yy > 191) ? 191 : yy);
    int xx = tx0 + cc - 1;
    xx = (xx < 0) ? 0 : ((xx > 383) ? 383 : xx);
    const float* fp = fb + (size_t)(32 + yy) * FW + (64 + xx);
    uint hiD[8], loD[8];
#pragma unroll
    for (int i = 0; i < 8; ++i) {
      float a0 = fp[(size_t)(2 * i) * FHW];
      float a1 = fp[(size_t)(2 * i + 1) * FHW];
      uint u0 = __float_as_uint(a0), u1 = __float_as_uint(a1);
      uint h0 = u0 & 0xFFFF0000u;
      uint h1 = u1 & 0xFFFF0000u;
      float l0 = a0 - __uint_as_float(h0);
      float l1 = a1 - __uint_as_float(h1);
      hiD[i] = (h0 >> 16) | h1;
      loD[i] = (__float_as_uint(l0) >> 16) | (__float_as_uint(l1) & 0xFFFF0000u);
    }
    int r72 = rr * 72;
    sH[r72 + swzslot(cc, 0)] = make_uint4(hiD[0], hiD[1], hiD[2], hiD[3]);
    sH[r72 + swzslot(cc, 1)] = make_uint4(hiD[4], hiD[5], hiD[6], hiD[7]);
    sL[r72 + swzslot(cc, 0)] = make_uint4(loD[0], loD[1], loD[2], loD[3]);
    sL[r72 + swzslot(cc, 1)] = make_uint4(loD[4], loD[5], loD[6], loD[7]);
  }
  __syncthreads();

  const short8* pH = (const short8*)sH;
  const short8* pL = (const short8*)sL;

  const int SH_[4] = {96, 128, 160, 192};
  const int SW_[4] = {192, 256, 320, 384};
  const int OY[4] = {48, 32, 16, 0};
  const int OX[4] = {96, 64, 32, 0};
  const float* BIAS[4] = {b0c, b1c, b2c, b3c};
  float* GD_[4] = {g0, g1, g2, g3};

#pragma unroll
  for (int st = 0; st < 4; ++st) {
    int sh = SH_[st], sw = SW_[st], oy = OY[st], ox = OX[st];
    bool inR = (ty0 >= oy) && (ty0 + 16 <= oy + sh) && (tx0 >= ox) &&
               (tx0 + 32 <= ox + sw);
    if (!inR) continue;  // block-uniform
    bool topE = (ty0 == oy), botE = (ty0 + 16 == oy + sh);
    bool leftE = (tx0 == ox), rightE = (tx0 + 32 == ox + sw);

    const short8* wfs = wf + st * 640;
    short8 WH[5], WL[5];
#pragma unroll
    for (int t = 0; t < 5; ++t) {
      WH[t] = wfs[(t * 2 + 0) * 64 + lane];
      WL[t] = wfs[(t * 2 + 1) * 64 + lane];
    }
    float bias4[4];
    {
      const float* bp = BIAS[st] + ((g & 1) << 2);
#pragma unroll
      for (int r = 0; r < 4; ++r) bias4[r] = bp[r];
    }
    size_t hw = (size_t)sh * sw;
    float* guid = GD_[st];

    // col-slot precompute (once per stage): xt in {0,1}, dx in {-1,0,+1}
    int csl[2][3];
#pragma unroll
    for (int xt = 0; xt < 2; ++xt) {
      int cc0 = (xt << 4) + px + 1;
      int ccm = (leftE && cc0 == 1) ? cc0 + 1 : cc0 - 1;
      int ccp = (rightE && cc0 == 32) ? cc0 - 1 : cc0 + 1;
      csl[xt][0] = swzslot(ccm, h_);
      csl[xt][1] = swzslot(cc0, h_);
      csl[xt][2] = swzslot(ccp, h_);
    }

#pragma unroll
    for (int i = 0; i < 8; ++i) {
      int tau = wv * 8 + i;
      int row = tau >> 1;
      const int xt = i & 1;  // wv*8 even -> compile-time per i
      int rr0 = row + 1;
      int rm = (topE && row == 0) ? rr0 + 1 : rr0 - 1;
      int rp = (botE && row == 15) ? rr0 - 1 : rr0 + 1;
      int rbm = rm * 72, rb_ = rr0 * 72, rbp = rp * 72;
      const int c0 = csl[xt][0], c1 = csl[xt][1], c2 = csl[xt][2];
      // E taps: (-1,-1)(-1,+1)(0,0)(+1,-1)(+1,+1); O: (-1,0)(0,-1)(0,+1)(+1,0)(dummy)
      int iE[5] = {rbm + c0, rbm + c2, rb_ + c1, rbp + c0, rbp + c2};
      int iO[5] = {rbm + c1, rb_ + c0, rb_ + c2, rbp + c1, rb_ + c1};

      f32x4 acc = {bias4[0], bias4[1], bias4[2], bias4[3]};
#pragma unroll
      for (int t = 0; t < 5; ++t) {
        int idx = gb ? iO[t] : iE[t];
        short8 fh = pH[idx];
        short8 fl = pL[idx];
        acc = __builtin_amdgcn_mfma_f32_16x16x32_bf16(WH[t], fh, acc, 0, 0, 0);
        acc = __builtin_amdgcn_mfma_f32_16x16x32_bf16(WH[t], fl, acc, 0, 0, 0);
        acc = __builtin_amdgcn_mfma_f32_16x16x32_bf16(WL[t], fh, acc, 0, 0, 0);
      }
      if (g < 2) {
        int ly = ty0 + row - oy, lx = tx0 + (xt << 4) + px - ox;
        float* gp = guid + (size_t)b * 8 * hw + (size_t)ly * sw + lx;
#pragma unroll
        for (int r = 0; r < 4; ++r) {
          int oo = g * 4 + r;
          float v = acc[r];
          v = (v > 0.0f) ? v : (__expf(v) - 1.0f);
          gp[(size_t)oo * hw] = v;
        }
      }
    }
  }
}

// ---------------- fused CSPN x3 with register gates: 16x16 tiles ------------
__global__ __launch_bounds__(256) void cspn3_kernel(
    const float* __restrict__ guid, const float* __restrict__ raw,
    const float* __restrict__ rgb, float* __restrict__ dst, int h, int w,
    int hs, int wss, int h2, int w2, int ph, int pw, int last, int py0,
    int py1, int px0, int px1) {
  __shared__ float sraw[LD * LD];
  __shared__ float s0[LD * LD];
  __shared__ float s1[LD * LD];

  int tpw = w / TW, tph = h / TH;
  int tile = blockIdx.x;
  int tx = tile % tpw;
  int t2 = tile / tpw;
  int ty = t2 % tph;
  int b = t2 / tph;
  int oy = ty * TH - HALO, ox = tx * TW - HALO;
  int tid = threadIdx.x;

  const float* rb = raw + (size_t)b * h * w;
  const float* rgb0 = rgb + ((size_t)b * 3) * FH * FW;

  for (int e = tid; e < LD * LD; e += 256) {
    int r = e / LD, c = e % LD;
    int gy = oy + r, gx = ox + c;
    bool in = (gy >= 0 && gy < h && gx >= 0 && gx < w);
    float v = 0.0f;
    if (in) {
      bool prev = (gy >= py0 && gy < py1 && gx >= px0 && gx < px1);
      v = prev ? rb[(size_t)gy * w + gx]
               : rgb0[(size_t)(hs + gy) * FW + (wss + gx)];
    }
    sraw[e] = v;
  }
  __syncthreads();

  const int dy8[8] = {1, 1, 1, 0, 0, -1, -1, -1};
  const int dx8[8] = {1, 0, -1, 1, -1, 1, 0, -1};
  const int off8[8] = {LD + 1, LD, LD - 1, 1, -1, -LD + 1, -LD, -LD - 1};

  const float* gb = guid + (size_t)b * 8 * h * w;
  float cg[MAXC][8];
  float r0[MAXC];
  int adr[MAXC];
#pragma unroll
  for (int ch = 0; ch < MAXC; ++ch) {
    int p = tid + ch * 256;
    bool ok = p < GD * GD;
    int pp = ok ? p : 0;
    int py = pp / GD + 1, px = pp % GD + 1;
    adr[ch] = py * LD + px;
    int gy = oy + py, gx = ox + px;
    bool in = ok && gy >= 0 && gy < h && gx >= 0 && gx < w;
    float wsum = 0.0f, asum = 0.0f;
    float g[8];
#pragma unroll
    for (int k = 0; k < 8; ++k) {
      int ny = gy + dy8[k], nx = gx + dx8[k];
      bool nin = ok && ny >= 0 && ny < h && nx >= 0 && nx < w;
      float gk = nin ? gb[(size_t)k * h * w + (size_t)ny * w + nx] : 0.0f;
      g[k] = gk;
      wsum += gk;
      asum += fabsf(gk);
    }
    float inv = in ? (1.0f / asum) : 0.0f;
#pragma unroll
    for (int k = 0; k < 8; ++k) cg[ch][k] = g[k] * inv;
    r0[ch] = in ? (1.0f - wsum * inv) * sraw[adr[ch]] : 0.0f;
  }

  // ---- iter 1: sraw -> s0 over 20x20 ----
#pragma unroll
  for (int ch = 0; ch < MAXC; ++ch) {
    int p = tid + ch * 256;
    if (p < GD * GD) {
      float v = r0[ch];
#pragma unroll
      for (int k = 0; k < 8; ++k) v += cg[ch][k] * sraw[adr[ch] + off8[k]];
      s0[adr[ch]] = v;
    }
  }
  __syncthreads();

  // ---- iter 2: s0 -> s1 over [2,19]^2 ----
#pragma unroll
  for (int ch = 0; ch < MAXC; ++ch) {
    int p = tid + ch * 256;
    if (p < GD * GD) {
      int py = p / GD + 1, px = p % GD + 1;
      if (py >= 2 && py <= LD - 3 && px >= 2 && px <= LD - 3) {
        float v = r0[ch];
#pragma unroll
        for (int k = 0; k < 8; ++k) v += cg[ch][k] * s0[adr[ch] + off8[k]];
        s1[adr[ch]] = v;
      }
    }
  }
  __syncthreads();

  // ---- iter 3 + epilogue over the 16x16 core ----
#pragma unroll
  for (int ch = 0; ch < MAXC; ++ch) {
    int p = tid + ch * 256;
    if (p < GD * GD) {
      int py = p / GD + 1, px = p % GD + 1;
      if (py >= 3 && py <= LD - 4 && px >= 3 && px <= LD - 4) {
        float v = r0[ch];
#pragma unroll
        for (int k = 0; k < 8; ++k) v += cg[ch][k] * s1[adr[ch] + off8[k]];
        float dl = fminf(fmaxf(v, 0.0f), 1.0f);
        int gy = oy + py, gx = ox + px;
        if (last) {
          dst[((size_t)b * h + gy) * w + gx] = dl;
        } else {
          float dep = rgb0[(size_t)(hs + gy) * FW + (wss + gx)];
          dst[((size_t)b * h2 + (gy + ph)) * w2 + (gx + pw)] =
              (dl > 0.0f) ? dl : dep;
        }
      }
    }
  }
}

// ---------------------------------------------------------------------------
extern "C" void kernel_launch(void* const* d_in, const int* in_sizes, int n_in,
                              void* d_out, int out_size, void* d_ws,
                              size_t ws_size, hipStream_t stream) {
  (void)in_sizes; (void)n_in; (void)out_size; (void)ws_size;
  const float* feat = (const float*)d_in[0];
  const float* blur = (const float*)d_in[1];
  const float* gt = (const float*)d_in[2];
  const float* rgb = (const float*)d_in[3];
  const float* W[4] = {(const float*)d_in[5], (const float*)d_in[7],
                       (const float*)d_in[9], (const float*)d_in[11]};
  const float* Bs[4] = {(const float*)d_in[6], (const float*)d_in[8],
                        (const float*)d_in[10], (const float*)d_in[12]};
  float* out = (float*)d_out;

  float* G0 = (float*)d_ws;
  float* G1 = G0 + (size_t)B * 8 * 96 * 192;
  float* G2 = G1 + (size_t)B * 8 * 128 * 256;
  float* G3 = G2 + (size_t)B * 8 * 160 * 320;
  float* RAW[4];
  RAW[0] = G3 + (size_t)B * 8 * 192 * 384;
  RAW[1] = RAW[0] + (size_t)B * 96 * 192;
  RAW[2] = RAW[1] + (size_t)B * 128 * 256;
  RAW[3] = RAW[2] + (size_t)B * 160 * 320;
  short8* WF = (short8*)(RAW[3] + (size_t)B * 192 * 384);
  float* G[4] = {G0, G1, G2, G3};

  const int CH[4] = {96, 128, 160, 192};
  const int CW[4] = {192, 256, 320, 384};

  prep_all_kernel<<<1152, 256, 0, stream>>>(gt, blur, rgb, W[0], W[1], W[2],
                                            W[3], WF, RAW[0]);

  conv_mfma_kernel<<<2304, 256, 0, stream>>>(feat, WF, Bs[0], G0, Bs[1], G1,
                                             Bs[2], G2, Bs[3], G3);

  for (int i = 0; i < 4; ++i) {
    int h = CH[i], w = CW[i];
    int hs = (FH - h) / 2, wss = (FW - w) / 2;
    int ntiles = B * (h / TH) * (w / TW);
    int py0 = 0, py1 = h, px0 = 0, px1 = w;
    if (i > 0) { py0 = 16; py1 = h - 16; px0 = 32; px1 = w - 32; }
    if (i < 3) {
      int h2 = CH[i + 1], w2 = CW[i + 1];
      int ph = (h2 - h) / 2, pw = (w2 - w) / 2;
      cspn3_kernel<<<ntiles, 256, 0, stream>>>(G[i], RAW[i], rgb, RAW[i + 1],
                                               h, w, hs, wss, h2, w2, ph, pw,
                                               0, py0, py1, px0, px1);
    } else {
      cspn3_kernel<<<ntiles, 256, 0, stream>>>(G[i], RAW[i], rgb, out, h, w,
                                               hs, wss, h, w, 0, 0, 1, py0,
                                               py1, px0, px1);
    }
  }
}